// Round 6
// baseline (352.760 us; speedup 1.0000x reference)
//
#include <hip/hip_runtime.h>

// Problem constants
#define BB    128
#define CC    272
#define TT    512
#define DD1   320
#define KC    32      // K-chunk per LDS stage (one mfma K)
#define NCHUNK 9      // ceil(272/32): K zero-padded to 288 (exact)
#define NT    64      // t-tile per block
#define MT    160     // d-tile per block (D1 split in 2)
#define LDA   40      // As row stride, bf16 elems (80 B: 16B-aligned, free-read banks)
#define LDB2  66      // Bs row stride, f32 elems (264 B: 8B-aligned, free-read banks)

typedef float  f32x4  __attribute__((ext_vector_type(4)));
typedef __bf16 bf16x4 __attribute__((ext_vector_type(4)));
typedef __bf16 bf16x8 __attribute__((ext_vector_type(8)));

// Raw barrier: orders LDS ops (lgkmcnt(0)) without draining vmcnt — keeps
// register-prefetch global loads in flight across the barrier.
#define BAR() asm volatile("s_waitcnt lgkmcnt(0)\ns_barrier" ::: "memory")

// out[b,d,t] = sum_c W[s_b,d,c] * X[b,c,t]
// 2048 blocks (1D, XCD-chunked decode), 256 thr / 4 waves as 2(m) x 2(n).
// SINGLE-buffered LDS (21.25 KB): the pa/pb register prefetch set IS the
// second buffer. 6 blocks/CU resident (VGPR-capped; was 3 with double-buf)
// = 24 waves/CU — the latency-hiding TLP every prior variant lacked.
// Chunk loop: compute(k) | BAR (reads done) | store k+1 from regs (vmcnt
// wait sits here; other blocks fill it) | issue loads k+2 | BAR (writes
// visible). XCD-chunked bid mapping keeps X[b] L2-resident (FETCH 88->51MB).
__global__ __launch_bounds__(256, 6)
void subj_conv_mfma(const float* __restrict__ X,
                    const int*   __restrict__ sidx,
                    const float* __restrict__ W,
                    float*       __restrict__ out) {
    const int bid  = blockIdx.x;                 // 0..2047
    // bid = ((b>>3)*16 + tile)*8 + (b&7)  — bijective over 128 b x 16 tiles
    const int b    = (bid & 7) + 8 * (bid >> 7);
    const int tile = (bid >> 3) & 15;
    const int T0   = (tile >> 1) * NT;
    const int d0   = (tile & 1) * MT;
    const int s    = sidx[b];

    __shared__ __align__(16) __bf16 As[MT * LDA];    // 12.8 KB, bf16 [m][kk]
    __shared__ __align__(16) float  Bs[KC * LDB2];   // 8.45 KB, fp32 natural [c][t]

    const int tid  = threadIdx.x;
    const int lane = tid & 63;
    const int wv   = tid >> 6;
    const int wm   = wv & 1;          // m-half (80 rows)
    const int wn   = wv >> 1;         // n-half (32 t)
    const int quad = lane >> 4;
    const int l16  = lane & 15;

    const float* Wb = W + ((size_t)s * DD1 + d0) * CC;
    const float* Xb = X + (size_t)b * CC * TT + T0;

    // A staging map: p<5: m = (tid>>3)+32p, kk = (tid&7)*4
    const int am  = tid >> 3;
    const int akk = (tid & 7) * 4;
    // B staging map: p<2: c-row = (tid>>4)+16p, t = (tid&15)*4
    const int bcr = tid >> 4;
    const int bt  = (tid & 15) * 4;

    f32x4 acc[5][2];
#pragma unroll
    for (int mt = 0; mt < 5; ++mt) {
        acc[mt][0] = (f32x4){0.f, 0.f, 0.f, 0.f};
        acc[mt][1] = (f32x4){0.f, 0.f, 0.f, 0.f};
    }

    float4 pa[5];
    float4 pb[2];

    // ---- issue global loads for chunk at c0 into pa/pb (all dwordx4)
    auto load_chunk = [&](int c0) {
#pragma unroll
        for (int p = 0; p < 5; ++p) {
            const int m = am + 32 * p;
            const int c = c0 + akk;
            float4 v = make_float4(0.f, 0.f, 0.f, 0.f);
            if (c < CC) v = *(const float4*)(Wb + (size_t)m * CC + c);
            pa[p] = v;
        }
#pragma unroll
        for (int p = 0; p < 2; ++p) {
            const int c = c0 + bcr + 16 * p;
            float4 v = make_float4(0.f, 0.f, 0.f, 0.f);
            if (c < CC) v = *(const float4*)(Xb + (size_t)c * TT + bt);
            pb[p] = v;
        }
    };

    // ---- cvt/store regs into the (single) LDS buffer
    auto store_chunk = [&]() {
#pragma unroll
        for (int p = 0; p < 5; ++p) {
            const int m = am + 32 * p;
            bf16x4 h = {(__bf16)pa[p].x, (__bf16)pa[p].y,
                        (__bf16)pa[p].z, (__bf16)pa[p].w};
            *(bf16x4*)&As[m * LDA + akk] = h;            // b64, ~2-way banks
        }
#pragma unroll
        for (int p = 0; p < 2; ++p) {
            const int cr = bcr + 16 * p;
            float* row = &Bs[cr * LDB2 + bt];            // natural layout, b64 x2
            *(float2*)(row + 0) = make_float2(pb[p].x, pb[p].y);
            *(float2*)(row + 2) = make_float2(pb[p].z, pb[p].w);
        }
    };

    auto compute = [&]() {
        // B-frags: gather 8 f32 per frag from natural [c][t] (2-way banks, free)
        bf16x8 bfr[2];
#pragma unroll
        for (int nt = 0; nt < 2; ++nt) {
            const int tcol = wn * 32 + nt * 16 + l16;
            bf16x8 h;
#pragma unroll
            for (int j = 0; j < 8; ++j)
                h[j] = (__bf16)Bs[(quad * 8 + j) * LDB2 + tcol];
            bfr[nt] = h;
        }
#pragma unroll
        for (int mt = 0; mt < 5; ++mt) {
            bf16x8 af = *(const bf16x8*)&As[(wm * 80 + mt * 16 + l16) * LDA + quad * 8];
#pragma unroll
            for (int nt = 0; nt < 2; ++nt)
                acc[mt][nt] = __builtin_amdgcn_mfma_f32_16x16x32_bf16(
                    af, bfr[nt], acc[mt][nt], 0, 0, 0);
        }
    };

    // ---- pipeline fill: chunk 0 staged; chunk 1 in flight in regs
    load_chunk(0);
    store_chunk();           // vmcnt wait here (fill cost, once)
    load_chunk(KC);          // chunk 1 in flight across barrier
    BAR();                   // chunk 0 visible

    for (int kc = 0; kc < NCHUNK; ++kc) {
        compute();                                // chunk kc from LDS
        if (kc + 1 < NCHUNK) {
            BAR();                                // all waves done READING LDS
            store_chunk();                        // overwrite with chunk kc+1
            if (kc + 2 < NCHUNK) load_chunk((kc + 2) * KC);
            BAR();                                // chunk kc+1 visible
        }
    }

    // ---- epilogue (R0-proven): D[m = quad*4 + r][n = l16], scalar stores
#pragma unroll
    for (int mt = 0; mt < 5; ++mt) {
        const int d = d0 + wm * 80 + mt * 16 + quad * 4;
#pragma unroll
        for (int nt = 0; nt < 2; ++nt) {
            float* ob = out + ((size_t)b * DD1 + d) * TT + T0 + wn * 32 + nt * 16 + l16;
#pragma unroll
            for (int r = 0; r < 4; ++r)
                ob[(size_t)r * TT] = acc[mt][nt][r];
        }
    }
}

extern "C" void kernel_launch(void* const* d_in, const int* in_sizes, int n_in,
                              void* d_out, int out_size, void* d_ws, size_t ws_size,
                              hipStream_t stream) {
    const float* X    = (const float*)d_in[0];   // [B, C, T]
    const int*   sidx = (const int*)  d_in[1];   // [B]
    const float* W    = (const float*)d_in[2];   // [S, D1, C]
    float*       out  = (float*)d_out;           // [B, D1, T]

    dim3 grid(BB * (TT / NT) * 2);   // 2048 blocks, XCD-chunked decode in-kernel
    dim3 block(256);
    subj_conv_mfma<<<grid, block, 0, stream>>>(X, sidx, W, out);
}

// Round 7
// 170.205 us; speedup vs baseline: 2.0726x; 2.0726x over previous
//
#include <hip/hip_runtime.h>

// Problem constants
#define BB    128
#define CC    272
#define TT    512
#define DD1   320
#define KC    32      // K-chunk per LDS stage (one mfma K)
#define NCHUNK 9      // ceil(272/32): K zero-padded to 288 (exact)
#define NT    64      // t-tile per block
#define MT    160     // d-tile per block (D1 split in 2)
#define LDA   40      // As row stride, bf16 elems (80 B: 16B-aligned, free-read banks)
#define LDB2  66      // Bs row stride, f32 elems (264 B: 8B-aligned, free-read banks)

typedef float  f32x4  __attribute__((ext_vector_type(4)));
typedef __bf16 bf16x4 __attribute__((ext_vector_type(4)));
typedef __bf16 bf16x8 __attribute__((ext_vector_type(8)));

// Raw barrier: orders LDS ops (lgkmcnt(0)) without draining vmcnt — keeps
// register-prefetch global loads in flight across the barrier.
#define BAR() asm volatile("s_waitcnt lgkmcnt(0)\ns_barrier" ::: "memory")

// out[b,d,t] = sum_c W[s_b,d,c] * X[b,c,t]
// 2048 blocks (1D, XCD-chunked decode), 256 thr / 4 waves as 2(m) x 2(n).
// SINGLE-buffered LDS (21.25 KB): the pa/pb register prefetch set IS the
// second buffer. With (256,4) bounds the kernel compiles to ~84 VGPR (R0-
// proven, no spills), which naturally allows 6 waves/SIMD -> 6 blocks/CU
// (LDS would allow 7) = ~2x the TLP of the double-buffered variants.
// R6's (256,6) forced a 40-VGPR allocation and spilled everything (608 MB
// scratch writes) — occupancy must come from LDS, not allocator pressure.
// Chunk loop: compute(k) | BAR | store k+1 from regs | issue loads k+2 | BAR.
// XCD-chunked bid mapping keeps X[b] L2-resident (FETCH 88->51MB, proven).
__global__ __launch_bounds__(256, 4)
void subj_conv_mfma(const float* __restrict__ X,
                    const int*   __restrict__ sidx,
                    const float* __restrict__ W,
                    float*       __restrict__ out) {
    const int bid  = blockIdx.x;                 // 0..2047
    // bid = ((b>>3)*16 + tile)*8 + (b&7)  — bijective over 128 b x 16 tiles
    const int b    = (bid & 7) + 8 * (bid >> 7);
    const int tile = (bid >> 3) & 15;
    const int T0   = (tile >> 1) * NT;
    const int d0   = (tile & 1) * MT;
    const int s    = sidx[b];

    __shared__ __align__(16) __bf16 As[MT * LDA];    // 12.8 KB, bf16 [m][kk]
    __shared__ __align__(16) float  Bs[KC * LDB2];   // 8.45 KB, fp32 natural [c][t]

    const int tid  = threadIdx.x;
    const int lane = tid & 63;
    const int wv   = tid >> 6;
    const int wm   = wv & 1;          // m-half (80 rows)
    const int wn   = wv >> 1;         // n-half (32 t)
    const int quad = lane >> 4;
    const int l16  = lane & 15;

    const float* Wb = W + ((size_t)s * DD1 + d0) * CC;
    const float* Xb = X + (size_t)b * CC * TT + T0;

    // A staging map: p<5: m = (tid>>3)+32p, kk = (tid&7)*4
    const int am  = tid >> 3;
    const int akk = (tid & 7) * 4;
    // B staging map: p<2: c-row = (tid>>4)+16p, t = (tid&15)*4
    const int bcr = tid >> 4;
    const int bt  = (tid & 15) * 4;

    f32x4 acc[5][2];
#pragma unroll
    for (int mt = 0; mt < 5; ++mt) {
        acc[mt][0] = (f32x4){0.f, 0.f, 0.f, 0.f};
        acc[mt][1] = (f32x4){0.f, 0.f, 0.f, 0.f};
    }

    float4 pa[5];
    float4 pb[2];

    // ---- issue global loads for chunk at c0 into pa/pb (all dwordx4)
    auto load_chunk = [&](int c0) {
#pragma unroll
        for (int p = 0; p < 5; ++p) {
            const int m = am + 32 * p;
            const int c = c0 + akk;
            float4 v = make_float4(0.f, 0.f, 0.f, 0.f);
            if (c < CC) v = *(const float4*)(Wb + (size_t)m * CC + c);
            pa[p] = v;
        }
#pragma unroll
        for (int p = 0; p < 2; ++p) {
            const int c = c0 + bcr + 16 * p;
            float4 v = make_float4(0.f, 0.f, 0.f, 0.f);
            if (c < CC) v = *(const float4*)(Xb + (size_t)c * TT + bt);
            pb[p] = v;
        }
    };

    // ---- cvt/store regs into the (single) LDS buffer
    auto store_chunk = [&]() {
#pragma unroll
        for (int p = 0; p < 5; ++p) {
            const int m = am + 32 * p;
            bf16x4 h = {(__bf16)pa[p].x, (__bf16)pa[p].y,
                        (__bf16)pa[p].z, (__bf16)pa[p].w};
            *(bf16x4*)&As[m * LDA + akk] = h;            // b64, ~2-way banks
        }
#pragma unroll
        for (int p = 0; p < 2; ++p) {
            const int cr = bcr + 16 * p;
            float* row = &Bs[cr * LDB2 + bt];            // natural layout, b64 x2
            *(float2*)(row + 0) = make_float2(pb[p].x, pb[p].y);
            *(float2*)(row + 2) = make_float2(pb[p].z, pb[p].w);
        }
    };

    auto compute = [&]() {
        // B-frags: gather 8 f32 per frag from natural [c][t] (2-way banks, free)
        bf16x8 bfr[2];
#pragma unroll
        for (int nt = 0; nt < 2; ++nt) {
            const int tcol = wn * 32 + nt * 16 + l16;
            bf16x8 h;
#pragma unroll
            for (int j = 0; j < 8; ++j)
                h[j] = (__bf16)Bs[(quad * 8 + j) * LDB2 + tcol];
            bfr[nt] = h;
        }
#pragma unroll
        for (int mt = 0; mt < 5; ++mt) {
            bf16x8 af = *(const bf16x8*)&As[(wm * 80 + mt * 16 + l16) * LDA + quad * 8];
#pragma unroll
            for (int nt = 0; nt < 2; ++nt)
                acc[mt][nt] = __builtin_amdgcn_mfma_f32_16x16x32_bf16(
                    af, bfr[nt], acc[mt][nt], 0, 0, 0);
        }
    };

    // ---- pipeline fill: chunk 0 staged; chunk 1 in flight in regs
    load_chunk(0);
    store_chunk();           // vmcnt wait here (fill cost, once)
    load_chunk(KC);          // chunk 1 in flight across barrier
    BAR();                   // chunk 0 visible

    for (int kc = 0; kc < NCHUNK; ++kc) {
        compute();                                // chunk kc from LDS
        if (kc + 1 < NCHUNK) {
            BAR();                                // all waves done READING LDS
            store_chunk();                        // overwrite with chunk kc+1
            if (kc + 2 < NCHUNK) load_chunk((kc + 2) * KC);
            BAR();                                // chunk kc+1 visible
        }
    }

    // ---- epilogue (R0-proven): D[m = quad*4 + r][n = l16], scalar stores
#pragma unroll
    for (int mt = 0; mt < 5; ++mt) {
        const int d = d0 + wm * 80 + mt * 16 + quad * 4;
#pragma unroll
        for (int nt = 0; nt < 2; ++nt) {
            float* ob = out + ((size_t)b * DD1 + d) * TT + T0 + wn * 32 + nt * 16 + l16;
#pragma unroll
            for (int r = 0; r < 4; ++r)
                ob[(size_t)r * TT] = acc[mt][nt][r];
        }
    }
}

extern "C" void kernel_launch(void* const* d_in, const int* in_sizes, int n_in,
                              void* d_out, int out_size, void* d_ws, size_t ws_size,
                              hipStream_t stream) {
    const float* X    = (const float*)d_in[0];   // [B, C, T]
    const int*   sidx = (const int*)  d_in[1];   // [B]
    const float* W    = (const float*)d_in[2];   // [S, D1, C]
    float*       out  = (float*)d_out;           // [B, D1, T]

    dim3 grid(BB * (TT / NT) * 2);   // 2048 blocks, XCD-chunked decode in-kernel
    dim3 block(256);
    subj_conv_mfma<<<grid, block, 0, stream>>>(X, sidx, W, out);
}

// Round 9
// 167.937 us; speedup vs baseline: 2.1005x; 1.0135x over previous
//
#include <hip/hip_runtime.h>

// Problem constants
#define BB    128
#define CC    272
#define CPAD  288     // K padded to 9*32 (rows 272..287 zeroed in LDS)
#define TT    512
#define DD1   320
#define NT    64      // t-tile per block
#define MT    160     // d-tile per block (D1 split in 2)
#define LDC   66      // Xs row stride, bf16 elems (132 B) -> 32-bank-perfect gathers

typedef float  f32x4  __attribute__((ext_vector_type(4)));
typedef __bf16 bf16x4 __attribute__((ext_vector_type(4)));
typedef __bf16 bf16x8 __attribute__((ext_vector_type(8)));

// ---- prepass: W f32 -> bf16 into workspace (8*320*272 elems, 340 blocks x 256 thr x 8)
__global__ __launch_bounds__(256)
void w_cvt(const float* __restrict__ W, __bf16* __restrict__ Wb) {
    const int i = blockIdx.x * 256 + threadIdx.x;      // 87040 threads
    const float4* src = (const float4*)W;
    const float4 a = src[2 * i];
    const float4 b = src[2 * i + 1];
    bf16x8 h = {(__bf16)a.x, (__bf16)a.y, (__bf16)a.z, (__bf16)a.w,
                (__bf16)b.x, (__bf16)b.y, (__bf16)b.z, (__bf16)b.w};
    *(bf16x8*)(Wb + 8 * i) = h;
}

// out[b,d,t] = sum_c W[s_b,d,c] * X[b,c,t]
// Grid (B, T/NT, 2), 256 thr / 4 waves as 2(m) x 2(n). BARRIER-FREE K-loop:
// - X tile (full K, bf16 [c][t], LDC=66: bank = c*33 + t/2 mod 32 -> the 64
//   lanes of a gather hit all 32 banks exactly once; pad rows 272..287 = 0)
//   is staged ONCE; one __syncthreads; then no sync for the rest.
// - W stays out of LDS: af fragments load global->reg (bf16x8, 16 B/lane,
//   L2-hot: W unique = 2.8 MB). 45 independent loads + 90 MFMA per wave
//   free-run -> memory parallelism no longer throttled by the chunk convoy
//   that pinned every prior variant at 66-85 us regardless of bytes/occup.
template <bool WB16>
__global__ __launch_bounds__(256, 4)
void subj_conv_mfma(const float*  __restrict__ X,
                    const int*    __restrict__ sidx,
                    const float*  __restrict__ W,
                    const __bf16* __restrict__ Wbf,
                    float*        __restrict__ out) {
    const int b  = blockIdx.x;
    const int T0 = blockIdx.y * NT;
    const int d0 = blockIdx.z * MT;
    const int s  = sidx[b];

    __shared__ __align__(16) __bf16 Xs[CPAD * LDC];   // 38,016 B -> 4 blocks/CU

    const int tid  = threadIdx.x;
    const int lane = tid & 63;
    const int wv   = tid >> 6;
    const int wm   = wv & 1;          // m-half (80 rows)
    const int wn   = wv >> 1;         // n-half (32 t)
    const int quad = lane >> 4;
    const int l16  = lane & 15;

    const float* Xb = X + (size_t)b * CC * TT + T0;

    // ---- stage full-K X tile once: f32 coalesced loads -> bf16 [c][t] rows.
    // 288 rows x 64 t / 256 thr = 18 passes; batched 6 to keep loads in flight.
    const int xr = tid >> 4;              // 0..15
    const int xt = (tid & 15) * 4;
#pragma unroll
    for (int pb = 0; pb < 3; ++pb) {
        float4 v[6];
#pragma unroll
        for (int q = 0; q < 6; ++q) {
            const int c = xr + 16 * (pb * 6 + q);
            v[q] = make_float4(0.f, 0.f, 0.f, 0.f);
            if (c < CC) v[q] = *(const float4*)(Xb + (size_t)c * TT + xt);
        }
#pragma unroll
        for (int q = 0; q < 6; ++q) {
            const int c = xr + 16 * (pb * 6 + q);
            bf16x4 h = {(__bf16)v[q].x, (__bf16)v[q].y,
                        (__bf16)v[q].z, (__bf16)v[q].w};
            *(bf16x4*)&Xs[c * LDC + xt] = h;      // b64, even-bank spread (free)
        }
    }
    __syncthreads();   // the ONLY barrier

    f32x4 acc[5][2];
#pragma unroll
    for (int mt = 0; mt < 5; ++mt) {
        acc[mt][0] = (f32x4){0.f, 0.f, 0.f, 0.f};
        acc[mt][1] = (f32x4){0.f, 0.f, 0.f, 0.f};
    }

    const int tc0 = wn * 32 + l16;        // t columns for the two n-frags
    const int tc1 = tc0 + 16;
    // per-lane W row base (d-row = d0 + wm*80 + mt*16 + l16, k-octet = quad*8)
    const size_t wrow = ((size_t)s * DD1 + d0 + wm * 80 + l16) * CC + quad * 8;
    const __bf16* Wp16 = Wbf + (WB16 ? wrow : 0);
    const float*  Wp32 = W   + (WB16 ? 0 : wrow);

#pragma unroll
    for (int kc = 0; kc < 9; ++kc) {
        // B-frags: elem j = X[kc*32 + quad*8 + j][T0 + tc] — conflict-free u16 gathers
        bf16x8 b0, b1;
#pragma unroll
        for (int j = 0; j < 8; ++j) {
            const int crow = (kc * 32 + quad * 8 + j) * LDC;
            b0[j] = Xs[crow + tc0];
            b1[j] = Xs[crow + tc1];
        }
#pragma unroll
        for (int mt = 0; mt < 5; ++mt) {
            const int off = mt * 16 * CC + kc * 32;   // elems, compile-time per unroll
            bf16x8 af = {(__bf16)0.f, (__bf16)0.f, (__bf16)0.f, (__bf16)0.f,
                         (__bf16)0.f, (__bf16)0.f, (__bf16)0.f, (__bf16)0.f};
            const bool live = (kc < 8) || (quad < 2);  // kc=8: k 256..287, valid only quads 0,1
            if (live) {
                if constexpr (WB16) {
                    af = *(const bf16x8*)(Wp16 + off);
                } else {
                    const float4 u0 = *(const float4*)(Wp32 + off);
                    const float4 u1 = *(const float4*)(Wp32 + off + 4);
                    af = bf16x8{(__bf16)u0.x, (__bf16)u0.y, (__bf16)u0.z, (__bf16)u0.w,
                                (__bf16)u1.x, (__bf16)u1.y, (__bf16)u1.z, (__bf16)u1.w};
                }
            }
            acc[mt][0] = __builtin_amdgcn_mfma_f32_16x16x32_bf16(af, b0, acc[mt][0], 0, 0, 0);
            acc[mt][1] = __builtin_amdgcn_mfma_f32_16x16x32_bf16(af, b1, acc[mt][1], 0, 0, 0);
        }
    }

    // ---- epilogue (R0-proven): D[m = quad*4 + r][n = l16], scalar stores
#pragma unroll
    for (int mt = 0; mt < 5; ++mt) {
        const int d = d0 + wm * 80 + mt * 16 + quad * 4;
#pragma unroll
        for (int nt = 0; nt < 2; ++nt) {
            float* ob = out + ((size_t)b * DD1 + d) * TT + T0 + wn * 32 + nt * 16 + l16;
#pragma unroll
            for (int r = 0; r < 4; ++r)
                ob[(size_t)r * TT] = acc[mt][nt][r];
        }
    }
}

extern "C" void kernel_launch(void* const* d_in, const int* in_sizes, int n_in,
                              void* d_out, int out_size, void* d_ws, size_t ws_size,
                              hipStream_t stream) {
    const float* X    = (const float*)d_in[0];   // [B, C, T]
    const int*   sidx = (const int*)  d_in[1];   // [B]
    const float* W    = (const float*)d_in[2];   // [S, D1, C]
    float*       out  = (float*)d_out;           // [B, D1, T]

    dim3 grid(BB, TT / NT, 2);   // 128 x 8 x 2 = 2048 blocks
    dim3 block(256);

    const size_t need = (size_t)8 * DD1 * CC * sizeof(__bf16);   // 1,392,640 B
    if (d_ws && ws_size >= need) {
        __bf16* Wb = (__bf16*)d_ws;
        w_cvt<<<dim3(340), dim3(256), 0, stream>>>(W, Wb);       // 8*320*272/8/256
        subj_conv_mfma<true><<<grid, block, 0, stream>>>(X, sidx, W, Wb, out);
    } else {
        subj_conv_mfma<false><<<grid, block, 0, stream>>>(X, sidx, W, nullptr, out);
    }
}